// Round 1
// baseline (399.027 us; speedup 1.0000x reference)
//
#include <hip/hip_runtime.h>

#define N_SPK 1024
#define M_UTT 16
#define D_DIM 512

#define ROWS 64
#define KTILE 128
#define DK 64

__device__ __forceinline__ float wave_sum64(float v) {
  #pragma unroll
  for (int off = 32; off >= 1; off >>= 1) v += __shfl_xor(v, off, 64);
  return v;
}

// Kernel 1: per speaker n — column sums S, centroid unit vector, per-utterance
// inverse norm and the leave-one-out diagonal term (stored as pos = w*(diag+eps)+b).
__global__ __launch_bounds__(256) void prep_kernel(
    const float* __restrict__ emb, const float* __restrict__ wp,
    const float* __restrict__ bp, float* __restrict__ c_unit,
    float* __restrict__ inv_norm, float* __restrict__ pos_out)
{
  const int n = blockIdx.x;
  const int t = threadIdx.x;
  __shared__ float es[M_UTT * D_DIM];
  __shared__ float Sd[D_DIM];
  __shared__ float red[4];

  const float* base = emb + (size_t)n * (M_UTT * D_DIM);
  #pragma unroll
  for (int i = 0; i < 8; ++i) {
    int s = t + i * 256;
    reinterpret_cast<float4*>(es)[s] = reinterpret_cast<const float4*>(base)[s];
  }
  __syncthreads();

  // S[d] = sum over m
  #pragma unroll
  for (int rep = 0; rep < 2; ++rep) {
    int d = t + rep * 256;
    float s = 0.f;
    #pragma unroll
    for (int m = 0; m < M_UTT; ++m) s += es[m * D_DIM + d];
    Sd[d] = s;
  }
  __syncthreads();

  // centroid norm
  float p = 0.f;
  #pragma unroll
  for (int rep = 0; rep < 2; ++rep) {
    int d = t + rep * 256;
    float c = Sd[d] * (1.f / M_UTT);
    p += c * c;
  }
  p = wave_sum64(p);
  if ((t & 63) == 0) red[t >> 6] = p;
  __syncthreads();
  float cn2 = red[0] + red[1] + red[2] + red[3];
  float invc = 1.f / fmaxf(sqrtf(cn2), 1e-8f);
  #pragma unroll
  for (int rep = 0; rep < 2; ++rep) {
    int d = t + rep * 256;
    c_unit[(size_t)n * D_DIM + d] = Sd[d] * (1.f / M_UTT) * invc;
  }

  // per-m: diag = e_unit . unit((S-e)/(M-1)), one m per wave round-robin
  const int wid = t >> 6, lane = t & 63;
  const float w = *wp, b = *bp;
  for (int m = wid; m < M_UTT; m += 4) {
    float dot = 0.f, ne = 0.f, nl = 0.f;
    #pragma unroll
    for (int r = 0; r < 8; ++r) {
      int d = lane + r * 64;
      float e = es[m * D_DIM + d];
      float l = Sd[d] - e;
      dot += e * l; ne += e * e; nl += l * l;
    }
    dot = wave_sum64(dot); ne = wave_sum64(ne); nl = wave_sum64(nl);
    if (lane == 0) {
      float inv_e = 1.f / fmaxf(sqrtf(ne), 1e-8f);
      float inv_l = 1.f / fmaxf(sqrtf(nl) * (1.f / (M_UTT - 1)), 1e-8f);
      float diag = dot * (1.f / (M_UTT - 1)) * inv_e * inv_l;
      pos_out[n * M_UTT + m] = w * (diag + 1e-6f) + b;
      inv_norm[n * M_UTT + m] = inv_e;
    }
  }
}

// Kernel 2: fused scores GEMM + exp-sum. Block = 512 threads, 64 rows (4 speakers)
// x all 1024 centroid columns, K-tiles of 128, D-chunks of 64 staged in LDS.
// Thread micro-tile: 4 rows x 4 cols. cs uses a 16B XOR swizzle.
__global__ __launch_bounds__(512) void main_kernel(
    const float* __restrict__ emb, const float* __restrict__ c_unit,
    const float* __restrict__ inv_norm, const float* __restrict__ pos,
    const float* __restrict__ wp, const float* __restrict__ bp,
    float* __restrict__ partials)
{
  const int t = threadIdx.x;
  const int rg = t >> 5;   // 0..15 -> rows rg*4..rg*4+3
  const int kt = t & 31;   // 0..31 -> cols kt + 32*j
  const int row0 = blockIdx.x * ROWS;

  __shared__ float cs[KTILE * DK];
  __shared__ float es[ROWS * DK];
  __shared__ float invn_l[ROWS];
  __shared__ float pos_l[ROWS];
  __shared__ float redbuf[16];

  if (t < ROWS) {
    invn_l[t] = inv_norm[row0 + t];
    pos_l[t] = pos[row0 + t];
  }

  const float w = *wp, b = *bp;
  const float bb = w * 1e-6f + b;   // folds the +SIM_EPS

  float expsum[4] = {0.f, 0.f, 0.f, 0.f};

  for (int ktile = 0; ktile < N_SPK / KTILE; ++ktile) {
    const int kbase = ktile * KTILE;
    float acc[4][4] = {};
    for (int dc = 0; dc < D_DIM / DK; ++dc) {
      const int db = dc * DK;
      __syncthreads();
      // stage centroid tile (128 x 64) with XOR swizzle on 16B slots
      #pragma unroll
      for (int i = 0; i < 4; ++i) {
        int s = t + i * 512;
        int k = s >> 4, seg = s & 15;
        float4 v = *reinterpret_cast<const float4*>(
            c_unit + (size_t)(kbase + k) * D_DIM + db + seg * 4);
        int off = k * 256 + ((seg * 16) ^ ((k & 15) << 4));
        *reinterpret_cast<float4*>(reinterpret_cast<char*>(cs) + off) = v;
      }
      // stage normalized embedding rows (64 x 64)
      #pragma unroll
      for (int i = 0; i < 2; ++i) {
        int s = t + i * 512;
        int r = s >> 4, seg = s & 15;
        float4 v = *reinterpret_cast<const float4*>(
            emb + (size_t)(row0 + r) * D_DIM + db + seg * 4);
        float sc = invn_l[r];
        v.x *= sc; v.y *= sc; v.z *= sc; v.w *= sc;
        *reinterpret_cast<float4*>(es + r * DK + seg * 4) = v;
      }
      __syncthreads();
      #pragma unroll 4
      for (int dd = 0; dd < DK / 4; ++dd) {
        float4 ev[4], cv[4];
        #pragma unroll
        for (int i = 0; i < 4; ++i)
          ev[i] = *reinterpret_cast<const float4*>(es + (rg * 4 + i) * DK + dd * 4);
        #pragma unroll
        for (int j = 0; j < 4; ++j) {
          int k = j * 32 + kt;
          int off = k * 256 + ((dd * 16) ^ ((k & 15) << 4));
          cv[j] = *reinterpret_cast<const float4*>(
              reinterpret_cast<const char*>(cs) + off);
        }
        #pragma unroll
        for (int i = 0; i < 4; ++i) {
          #pragma unroll
          for (int j = 0; j < 4; ++j) {
            acc[i][j] += ev[i].x * cv[j].x + ev[i].y * cv[j].y +
                         ev[i].z * cv[j].z + ev[i].w * cv[j].w;
          }
        }
      }
    }
    // fused exp-sum for this K-tile; substitute the diagonal column
    #pragma unroll
    for (int j = 0; j < 4; ++j) {
      int kg = kbase + j * 32 + kt;
      #pragma unroll
      for (int i = 0; i < 4; ++i) {
        int r = rg * 4 + i;
        float arg = w * acc[i][j] + bb;
        if (kg == ((row0 + r) >> 4)) arg = pos_l[r];
        expsum[i] += __expf(arg);
      }
    }
  }

  // reduce expsum across the 32 kt lanes (lanes 0-31 and 32-63 are separate rgs)
  #pragma unroll
  for (int i = 0; i < 4; ++i) {
    float v = expsum[i];
    #pragma unroll
    for (int off = 1; off < 32; off <<= 1) v += __shfl_xor(v, off, 64);
    expsum[i] = v;
  }
  if (kt == 0) {
    float local = 0.f;
    #pragma unroll
    for (int i = 0; i < 4; ++i) {
      int r = rg * 4 + i;
      local += logf(expsum[i] + 1e-6f) - pos_l[r];
    }
    redbuf[rg] = local;
  }
  __syncthreads();
  if (t == 0) {
    float s = 0.f;
    for (int i = 0; i < 16; ++i) s += redbuf[i];
    partials[blockIdx.x] = s;
  }
}

__global__ __launch_bounds__(256) void reduce_kernel(
    const float* __restrict__ partials, float* __restrict__ out)
{
  int t = threadIdx.x;
  float v = partials[t];
  v = wave_sum64(v);
  __shared__ float r[4];
  if ((t & 63) == 0) r[t >> 6] = v;
  __syncthreads();
  if (t == 0) out[0] = r[0] + r[1] + r[2] + r[3];
}

extern "C" void kernel_launch(void* const* d_in, const int* in_sizes, int n_in,
                              void* d_out, int out_size, void* d_ws, size_t ws_size,
                              hipStream_t stream) {
  const float* emb = (const float*)d_in[0];
  const float* wp  = (const float*)d_in[1];
  const float* bp  = (const float*)d_in[2];
  float* out = (float*)d_out;

  float* ws = (float*)d_ws;
  float* c_unit   = ws;                               // 1024*512 = 524288 floats
  float* inv_norm = ws + 524288;                      // 16384 floats
  float* pos      = ws + 524288 + 16384;              // 16384 floats
  float* partials = ws + 524288 + 2 * 16384;          // 256 floats

  prep_kernel<<<N_SPK, 256, 0, stream>>>(emb, wp, bp, c_unit, inv_norm, pos);
  main_kernel<<<(N_SPK * M_UTT) / ROWS, 512, 0, stream>>>(
      emb, c_unit, inv_norm, pos, wp, bp, partials);
  reduce_kernel<<<1, 256, 0, stream>>>(partials, out);
}

// Round 2
// 51.592 us; speedup vs baseline: 7.7342x; 7.7342x over previous
//
#include <hip/hip_runtime.h>

#define N_SPK 1024
#define M_UTT 16
#define D_DIM 512

typedef __attribute__((ext_vector_type(8))) short bf16x8;
typedef __attribute__((ext_vector_type(4))) float f32x4;

__device__ __forceinline__ float wave_sum64(float v) {
  #pragma unroll
  for (int off = 32; off >= 1; off >>= 1) v += __shfl_xor(v, off, 64);
  return v;
}

__device__ __forceinline__ unsigned short f2bf(float x) {
  unsigned int u = __float_as_uint(x);
  unsigned int r = (u + 0x7FFFu + ((u >> 16) & 1u)) >> 16;  // RNE
  return (unsigned short)r;
}

__device__ __forceinline__ unsigned int pack_bf16(float a, float b) {
  return (unsigned int)f2bf(a) | ((unsigned int)f2bf(b) << 16);
}

__device__ __forceinline__ void gload_lds16(const void* g, void* l) {
  __builtin_amdgcn_global_load_lds(
      (const __attribute__((address_space(1))) void*)g,
      (__attribute__((address_space(3))) void*)l, 16, 0, 0);
}

// Kernel 1: per speaker n — centroid unit vec (bf16), normalized embeddings
// (bf16), and the exact fp32 leave-one-out diagonal logit pos = w*(diag+eps)+b.
__global__ __launch_bounds__(256) void prep_kernel(
    const float* __restrict__ emb, const float* __restrict__ wp,
    const float* __restrict__ bp, unsigned int* __restrict__ eU,
    unsigned int* __restrict__ cU, float* __restrict__ pos_out)
{
  const int n = blockIdx.x;
  const int t = threadIdx.x;
  __shared__ float es[M_UTT * D_DIM];
  __shared__ float Sd[D_DIM];
  __shared__ float red[4];
  __shared__ float inv_s[M_UTT];

  const float* base = emb + (size_t)n * (M_UTT * D_DIM);
  #pragma unroll
  for (int i = 0; i < 8; ++i) {
    int s = t + i * 256;
    reinterpret_cast<float4*>(es)[s] = reinterpret_cast<const float4*>(base)[s];
  }
  __syncthreads();

  #pragma unroll
  for (int rep = 0; rep < 2; ++rep) {
    int d = t + rep * 256;
    float s = 0.f;
    #pragma unroll
    for (int m = 0; m < M_UTT; ++m) s += es[m * D_DIM + d];
    Sd[d] = s;
  }
  __syncthreads();

  float p = 0.f;
  #pragma unroll
  for (int rep = 0; rep < 2; ++rep) {
    int d = t + rep * 256;
    float c = Sd[d] * (1.f / M_UTT);
    p += c * c;
  }
  p = wave_sum64(p);
  if ((t & 63) == 0) red[t >> 6] = p;
  __syncthreads();
  float cn2 = red[0] + red[1] + red[2] + red[3];
  float invc = 1.f / fmaxf(sqrtf(cn2), 1e-8f);

  // centroid unit vector -> bf16 (2 elems per thread)
  {
    int d = t * 2;
    float c0 = Sd[d] * (1.f / M_UTT) * invc;
    float c1 = Sd[d + 1] * (1.f / M_UTT) * invc;
    cU[n * 256 + t] = pack_bf16(c0, c1);
  }

  // per-m diag (exact fp32) + inverse norms
  const int wid = t >> 6, lane = t & 63;
  const float w = *wp, b = *bp;
  for (int m = wid; m < M_UTT; m += 4) {
    float dot = 0.f, ne = 0.f, nl = 0.f;
    #pragma unroll
    for (int r = 0; r < 8; ++r) {
      int d = lane + r * 64;
      float e = es[m * D_DIM + d];
      float l = Sd[d] - e;
      dot += e * l; ne += e * e; nl += l * l;
    }
    dot = wave_sum64(dot); ne = wave_sum64(ne); nl = wave_sum64(nl);
    if (lane == 0) {
      float inv_e = 1.f / fmaxf(sqrtf(ne), 1e-8f);
      float inv_l = 1.f / fmaxf(sqrtf(nl) * (1.f / (M_UTT - 1)), 1e-8f);
      float diag = dot * (1.f / (M_UTT - 1)) * inv_e * inv_l;
      pos_out[n * M_UTT + m] = w * (diag + 1e-6f) + b;
      inv_s[m] = inv_e;
    }
  }
  __syncthreads();

  // normalized embeddings -> bf16 (16 iters x 2 elems)
  #pragma unroll
  for (int i = 0; i < 16; ++i) {
    int p2 = t + i * 256;            // pair index 0..4095
    int m = p2 >> 8;
    int d = (p2 & 255) * 2;
    float sc = inv_s[m];
    float x0 = es[m * D_DIM + d] * sc;
    float x1 = es[m * D_DIM + d + 1] * sc;
    eU[(size_t)n * 4096 + p2] = pack_bf16(x0, x1);
  }
}

// Kernel 2: bf16 MFMA GEMM (16384x1024x512) with fused exp epilogue.
// 128x128 block tile, BK=64, 4 waves (2x2), 64x64 per wave, 4x4 fragments.
// A/B staged via global_load_lds(16B) with pre-swizzled source; ds_read_b128
// with matching XOR swizzle (seg ^= row&7).
#define BM 128
#define BN 128
#define BK 64

__global__ __launch_bounds__(256) void mfma_kernel(
    const unsigned short* __restrict__ eU, const unsigned short* __restrict__ cU,
    const float* __restrict__ pos, const float* __restrict__ wp,
    const float* __restrict__ bp, float* __restrict__ partial)
{
  __shared__ unsigned short As[BM * BK];
  __shared__ unsigned short Bs[BN * BK];
  __shared__ float rowsum[2][BM];
  __shared__ float pos_l[BM];

  const int t = threadIdx.x;
  const int lane = t & 63;
  const int wv_id = t >> 6;            // 0..3
  const int wm = wv_id >> 1, wn = wv_id & 1;
  const int cb = blockIdx.x, rb = blockIdx.y;
  const int row0 = rb * BM, col0 = cb * BN;

  if (t < BM) pos_l[t] = pos[row0 + t];

  const float w = *wp, b = *bp;
  const float bb = w * 1e-6f + b;      // fold +SIM_EPS

  f32x4 acc[4][4] = {};

  const int lrow = lane >> 3;              // row within 8-row chunk
  const int lseg = (lane & 7) ^ lrow;      // pre-swizzled 16B-seg in source

  for (int kt = 0; kt < D_DIM / BK; ++kt) {
    const int d0 = kt * BK;
    __syncthreads();
    #pragma unroll
    for (int i = 0; i < 4; ++i) {
      int c = wv_id * 4 + i;               // chunk 0..15 (8 rows each)
      size_t gr = (size_t)(row0 + c * 8 + lrow) * D_DIM + d0 + lseg * 8;
      gload_lds16(eU + gr, (char*)As + c * 1024);
      size_t gc = (size_t)(col0 + c * 8 + lrow) * D_DIM + d0 + lseg * 8;
      gload_lds16(cU + gc, (char*)Bs + c * 1024);
    }
    __syncthreads();   // compiler drains vmcnt before barrier

    #pragma unroll
    for (int kk = 0; kk < 2; ++kk) {
      bf16x8 af[4], bf[4];
      #pragma unroll
      for (int mi = 0; mi < 4; ++mi) {
        int r = wm * 64 + mi * 16 + (lane & 15);
        int seg = ((lane >> 4) + kk * 4) ^ (r & 7);
        af[mi] = *reinterpret_cast<const bf16x8*>(
            (const char*)As + r * 128 + seg * 16);
      }
      #pragma unroll
      for (int nj = 0; nj < 4; ++nj) {
        int s = wn * 64 + nj * 16 + (lane & 15);
        int seg = ((lane >> 4) + kk * 4) ^ (s & 7);
        bf[nj] = *reinterpret_cast<const bf16x8*>(
            (const char*)Bs + s * 128 + seg * 16);
      }
      #pragma unroll
      for (int mi = 0; mi < 4; ++mi)
        #pragma unroll
        for (int nj = 0; nj < 4; ++nj)
          acc[mi][nj] = __builtin_amdgcn_mfma_f32_16x16x32_bf16(
              af[mi], bf[nj], acc[mi][nj], 0, 0, 0);
    }
  }

  // fused epilogue: arg = w*acc + bb (diag -> pos), exp, per-row sums
  float esum[4][4];
  #pragma unroll
  for (int mi = 0; mi < 4; ++mi)
    #pragma unroll
    for (int rg = 0; rg < 4; ++rg) esum[mi][rg] = 0.f;

  #pragma unroll
  for (int nj = 0; nj < 4; ++nj) {
    int kg = col0 + wn * 64 + nj * 16 + (lane & 15);
    #pragma unroll
    for (int mi = 0; mi < 4; ++mi) {
      #pragma unroll
      for (int rg = 0; rg < 4; ++rg) {
        int r_loc = wm * 64 + mi * 16 + (lane >> 4) * 4 + rg;
        float arg = w * acc[mi][nj][rg] + bb;
        if (kg == ((row0 + r_loc) >> 4)) arg = pos_l[r_loc];
        esum[mi][rg] += __expf(arg);
      }
    }
  }
  // reduce across the 16 column-lanes (same rows: lane bits 0-3)
  #pragma unroll
  for (int mi = 0; mi < 4; ++mi)
    #pragma unroll
    for (int rg = 0; rg < 4; ++rg) {
      float v = esum[mi][rg];
      v += __shfl_xor(v, 1, 64);
      v += __shfl_xor(v, 2, 64);
      v += __shfl_xor(v, 4, 64);
      v += __shfl_xor(v, 8, 64);
      esum[mi][rg] = v;
    }
  if ((lane & 15) == 0) {
    #pragma unroll
    for (int mi = 0; mi < 4; ++mi)
      #pragma unroll
      for (int rg = 0; rg < 4; ++rg)
        rowsum[wn][wm * 64 + mi * 16 + (lane >> 4) * 4 + rg] = esum[mi][rg];
  }
  __syncthreads();
  if (t < BM) partial[(size_t)cb * (N_SPK * M_UTT) + row0 + t] =
      rowsum[0][t] + rowsum[1][t];
}

__global__ __launch_bounds__(256) void finalize_kernel(
    const float* __restrict__ partial, const float* __restrict__ pos,
    float* __restrict__ bsum)
{
  const int t = threadIdx.x;
  const int r = blockIdx.x * 256 + t;
  float s = 0.f;
  #pragma unroll
  for (int cb = 0; cb < 8; ++cb) s += partial[cb * (N_SPK * M_UTT) + r];
  float v = logf(s + 1e-6f) - pos[r];
  v = wave_sum64(v);
  __shared__ float red[4];
  if ((t & 63) == 0) red[t >> 6] = v;
  __syncthreads();
  if (t == 0) bsum[blockIdx.x] = red[0] + red[1] + red[2] + red[3];
}

__global__ void final_reduce(const float* __restrict__ bsum,
                             float* __restrict__ out)
{
  float v = bsum[threadIdx.x];
  v = wave_sum64(v);
  if (threadIdx.x == 0) out[0] = v;
}

extern "C" void kernel_launch(void* const* d_in, const int* in_sizes, int n_in,
                              void* d_out, int out_size, void* d_ws, size_t ws_size,
                              hipStream_t stream) {
  const float* emb = (const float*)d_in[0];
  const float* wp  = (const float*)d_in[1];
  const float* bp  = (const float*)d_in[2];
  float* out = (float*)d_out;

  char* wsb = (char*)d_ws;
  unsigned int* eU  = (unsigned int*)wsb;                       // 16,777,216 B
  unsigned int* cU  = (unsigned int*)(wsb + 16777216);          //  1,048,576 B
  float* pos        = (float*)(wsb + 16777216 + 1048576);       //     65,536 B
  float* partial    = (float*)(wsb + 16777216 + 1048576 + 65536);   // 524,288 B
  float* bsum       = (float*)(wsb + 16777216 + 1048576 + 65536 + 524288);

  prep_kernel<<<N_SPK, 256, 0, stream>>>(emb, wp, bp, eU, cU, pos);
  dim3 grid(N_SPK / BN, (N_SPK * M_UTT) / BM);
  mfma_kernel<<<grid, 256, 0, stream>>>(
      (const unsigned short*)eU, (const unsigned short*)cU, pos, wp, bp, partial);
  finalize_kernel<<<(N_SPK * M_UTT) / 256, 256, 0, stream>>>(partial, pos, bsum);
  final_reduce<<<1, 64, 0, stream>>>(bsum, out);
}

// Round 3
// 51.522 us; speedup vs baseline: 7.7447x; 1.0014x over previous
//
#include <hip/hip_runtime.h>

#define N_SPK 1024
#define M_UTT 16
#define D_DIM 512

typedef __attribute__((ext_vector_type(8))) short bf16x8;
typedef __attribute__((ext_vector_type(4))) float f32x4;

__device__ __forceinline__ float wave_sum64(float v) {
  #pragma unroll
  for (int off = 32; off >= 1; off >>= 1) v += __shfl_xor(v, off, 64);
  return v;
}

__device__ __forceinline__ unsigned short f2bf(float x) {
  unsigned int u = __float_as_uint(x);
  unsigned int r = (u + 0x7FFFu + ((u >> 16) & 1u)) >> 16;  // RNE
  return (unsigned short)r;
}

__device__ __forceinline__ unsigned int pack_bf16(float a, float b) {
  return (unsigned int)f2bf(a) | ((unsigned int)f2bf(b) << 16);
}

__device__ __forceinline__ void gload_lds16(const void* g, void* l) {
  __builtin_amdgcn_global_load_lds(
      (const __attribute__((address_space(1))) void*)g,
      (__attribute__((address_space(3))) void*)l, 16, 0, 0);
}

// Kernel 1: per speaker n — centroid unit vec (bf16), normalized embeddings
// (bf16), and the exact fp32 leave-one-out diagonal logit pos = w*(diag+eps)+b.
__global__ __launch_bounds__(256) void prep_kernel(
    const float* __restrict__ emb, const float* __restrict__ wp,
    const float* __restrict__ bp, unsigned int* __restrict__ eU,
    unsigned int* __restrict__ cU, float* __restrict__ pos_out)
{
  const int n = blockIdx.x;
  const int t = threadIdx.x;
  __shared__ float es[M_UTT * D_DIM];
  __shared__ float Sd[D_DIM];
  __shared__ float red[4];
  __shared__ float inv_s[M_UTT];

  const float* base = emb + (size_t)n * (M_UTT * D_DIM);
  #pragma unroll
  for (int i = 0; i < 8; ++i) {
    int s = t + i * 256;
    reinterpret_cast<float4*>(es)[s] = reinterpret_cast<const float4*>(base)[s];
  }
  __syncthreads();

  #pragma unroll
  for (int rep = 0; rep < 2; ++rep) {
    int d = t + rep * 256;
    float s = 0.f;
    #pragma unroll
    for (int m = 0; m < M_UTT; ++m) s += es[m * D_DIM + d];
    Sd[d] = s;
  }
  __syncthreads();

  float p = 0.f;
  #pragma unroll
  for (int rep = 0; rep < 2; ++rep) {
    int d = t + rep * 256;
    float c = Sd[d] * (1.f / M_UTT);
    p += c * c;
  }
  p = wave_sum64(p);
  if ((t & 63) == 0) red[t >> 6] = p;
  __syncthreads();
  float cn2 = red[0] + red[1] + red[2] + red[3];
  float invc = 1.f / fmaxf(sqrtf(cn2), 1e-8f);

  // centroid unit vector -> bf16 (2 elems per thread)
  {
    int d = t * 2;
    float c0 = Sd[d] * (1.f / M_UTT) * invc;
    float c1 = Sd[d + 1] * (1.f / M_UTT) * invc;
    cU[n * 256 + t] = pack_bf16(c0, c1);
  }

  // per-m diag (exact fp32) + inverse norms
  const int wid = t >> 6, lane = t & 63;
  const float w = *wp, b = *bp;
  for (int m = wid; m < M_UTT; m += 4) {
    float dot = 0.f, ne = 0.f, nl = 0.f;
    #pragma unroll
    for (int r = 0; r < 8; ++r) {
      int d = lane + r * 64;
      float e = es[m * D_DIM + d];
      float l = Sd[d] - e;
      dot += e * l; ne += e * e; nl += l * l;
    }
    dot = wave_sum64(dot); ne = wave_sum64(ne); nl = wave_sum64(nl);
    if (lane == 0) {
      float inv_e = 1.f / fmaxf(sqrtf(ne), 1e-8f);
      float inv_l = 1.f / fmaxf(sqrtf(nl) * (1.f / (M_UTT - 1)), 1e-8f);
      float diag = dot * (1.f / (M_UTT - 1)) * inv_e * inv_l;
      pos_out[n * M_UTT + m] = w * (diag + 1e-6f) + b;
      inv_s[m] = inv_e;
    }
  }
  __syncthreads();

  // normalized embeddings -> bf16 (16 iters x 2 elems)
  #pragma unroll
  for (int i = 0; i < 16; ++i) {
    int p2 = t + i * 256;            // pair index 0..4095
    int m = p2 >> 8;
    int d = (p2 & 255) * 2;
    float sc = inv_s[m];
    float x0 = es[m * D_DIM + d] * sc;
    float x1 = es[m * D_DIM + d + 1] * sc;
    eU[(size_t)n * 4096 + p2] = pack_bf16(x0, x1);
  }
}

// Kernel 2: bf16 MFMA GEMM (16384x1024x512) with fused exp epilogue.
// 128x128 block tile, BK=64, 4 waves (2x2), 64x64 per wave, 4x4 fragments.
// A/B staged via global_load_lds(16B) with pre-swizzled source; ds_read_b128
// with matching XOR swizzle (seg ^= row&7).
#define BM 128
#define BN 128
#define BK 64

__global__ __launch_bounds__(256) void mfma_kernel(
    const unsigned short* __restrict__ eU, const unsigned short* __restrict__ cU,
    const float* __restrict__ pos, const float* __restrict__ wp,
    const float* __restrict__ bp, float* __restrict__ partial)
{
  __shared__ unsigned short As[BM * BK];
  __shared__ unsigned short Bs[BN * BK];
  __shared__ float rowsum[2][BM];
  __shared__ float pos_l[BM];

  const int t = threadIdx.x;
  const int lane = t & 63;
  const int wv_id = t >> 6;            // 0..3
  const int wm = wv_id >> 1, wn = wv_id & 1;
  const int cb = blockIdx.x, rb = blockIdx.y;
  const int row0 = rb * BM, col0 = cb * BN;

  if (t < BM) pos_l[t] = pos[row0 + t];

  const float w = *wp, b = *bp;
  const float bb = w * 1e-6f + b;      // fold +SIM_EPS

  f32x4 acc[4][4] = {};

  const int lrow = lane >> 3;              // row within 8-row chunk
  const int lseg = (lane & 7) ^ lrow;      // pre-swizzled 16B-seg in source

  for (int kt = 0; kt < D_DIM / BK; ++kt) {
    const int d0 = kt * BK;
    __syncthreads();
    #pragma unroll
    for (int i = 0; i < 4; ++i) {
      int c = wv_id * 4 + i;               // chunk 0..15 (8 rows each)
      size_t gr = (size_t)(row0 + c * 8 + lrow) * D_DIM + d0 + lseg * 8;
      gload_lds16(eU + gr, (char*)As + c * 1024);
      size_t gc = (size_t)(col0 + c * 8 + lrow) * D_DIM + d0 + lseg * 8;
      gload_lds16(cU + gc, (char*)Bs + c * 1024);
    }
    __syncthreads();   // compiler drains vmcnt before barrier

    #pragma unroll
    for (int kk = 0; kk < 2; ++kk) {
      bf16x8 af[4], bf[4];
      #pragma unroll
      for (int mi = 0; mi < 4; ++mi) {
        int r = wm * 64 + mi * 16 + (lane & 15);
        int seg = ((lane >> 4) + kk * 4) ^ (r & 7);
        af[mi] = *reinterpret_cast<const bf16x8*>(
            (const char*)As + r * 128 + seg * 16);
      }
      #pragma unroll
      for (int nj = 0; nj < 4; ++nj) {
        int s = wn * 64 + nj * 16 + (lane & 15);
        int seg = ((lane >> 4) + kk * 4) ^ (s & 7);
        bf[nj] = *reinterpret_cast<const bf16x8*>(
            (const char*)Bs + s * 128 + seg * 16);
      }
      #pragma unroll
      for (int mi = 0; mi < 4; ++mi)
        #pragma unroll
        for (int nj = 0; nj < 4; ++nj)
          acc[mi][nj] = __builtin_amdgcn_mfma_f32_16x16x32_bf16(
              af[mi], bf[nj], acc[mi][nj], 0, 0, 0);
    }
  }

  // fused epilogue: arg = w*acc + bb (diag -> pos), exp, per-row sums
  float esum[4][4];
  #pragma unroll
  for (int mi = 0; mi < 4; ++mi)
    #pragma unroll
    for (int rg = 0; rg < 4; ++rg) esum[mi][rg] = 0.f;

  #pragma unroll
  for (int nj = 0; nj < 4; ++nj) {
    int kg = col0 + wn * 64 + nj * 16 + (lane & 15);
    #pragma unroll
    for (int mi = 0; mi < 4; ++mi) {
      #pragma unroll
      for (int rg = 0; rg < 4; ++rg) {
        int r_loc = wm * 64 + mi * 16 + (lane >> 4) * 4 + rg;
        float arg = w * acc[mi][nj][rg] + bb;
        if (kg == ((row0 + r_loc) >> 4)) arg = pos_l[r_loc];
        esum[mi][rg] += __expf(arg);
      }
    }
  }
  // reduce across the 16 column-lanes (same rows: lane bits 0-3)
  #pragma unroll
  for (int mi = 0; mi < 4; ++mi)
    #pragma unroll
    for (int rg = 0; rg < 4; ++rg) {
      float v = esum[mi][rg];
      v += __shfl_xor(v, 1, 64);
      v += __shfl_xor(v, 2, 64);
      v += __shfl_xor(v, 4, 64);
      v += __shfl_xor(v, 8, 64);
      esum[mi][rg] = v;
    }
  if ((lane & 15) == 0) {
    #pragma unroll
    for (int mi = 0; mi < 4; ++mi)
      #pragma unroll
      for (int rg = 0; rg < 4; ++rg)
        rowsum[wn][wm * 64 + mi * 16 + (lane >> 4) * 4 + rg] = esum[mi][rg];
  }
  __syncthreads();
  if (t < BM) partial[(size_t)cb * (N_SPK * M_UTT) + row0 + t] =
      rowsum[0][t] + rowsum[1][t];
}

__global__ __launch_bounds__(256) void finalize_kernel(
    const float* __restrict__ partial, const float* __restrict__ pos,
    float* __restrict__ bsum)
{
  const int t = threadIdx.x;
  const int r = blockIdx.x * 256 + t;
  float s = 0.f;
  #pragma unroll
  for (int cb = 0; cb < 8; ++cb) s += partial[cb * (N_SPK * M_UTT) + r];
  float v = logf(s + 1e-6f) - pos[r];
  v = wave_sum64(v);
  __shared__ float red[4];
  if ((t & 63) == 0) red[t >> 6] = v;
  __syncthreads();
  if (t == 0) bsum[blockIdx.x] = red[0] + red[1] + red[2] + red[3];
}

__global__ void final_reduce(const float* __restrict__ bsum,
                             float* __restrict__ out)
{
  float v = bsum[threadIdx.x];
  v = wave_sum64(v);
  if (threadIdx.x == 0) out[0] = v;
}

extern "C" void kernel_launch(void* const* d_in, const int* in_sizes, int n_in,
                              void* d_out, int out_size, void* d_ws, size_t ws_size,
                              hipStream_t stream) {
  const float* emb = (const float*)d_in[0];
  const float* wp  = (const float*)d_in[1];
  const float* bp  = (const float*)d_in[2];
  float* out = (float*)d_out;

  char* wsb = (char*)d_ws;
  unsigned int* eU  = (unsigned int*)wsb;                       // 16,777,216 B
  unsigned int* cU  = (unsigned int*)(wsb + 16777216);          //  1,048,576 B
  float* pos        = (float*)(wsb + 16777216 + 1048576);       //     65,536 B
  float* partial    = (float*)(wsb + 16777216 + 1048576 + 65536);   // 524,288 B
  float* bsum       = (float*)(wsb + 16777216 + 1048576 + 65536 + 524288);

  prep_kernel<<<N_SPK, 256, 0, stream>>>(emb, wp, bp, eU, cU, pos);
  dim3 grid(N_SPK / BN, (N_SPK * M_UTT) / BM);
  mfma_kernel<<<grid, 256, 0, stream>>>(
      (const unsigned short*)eU, (const unsigned short*)cU, pos, wp, bp, partial);
  finalize_kernel<<<(N_SPK * M_UTT) / 256, 256, 0, stream>>>(partial, pos, bsum);
  final_reduce<<<1, 64, 0, stream>>>(bsum, out);
}

// Round 4
// 51.179 us; speedup vs baseline: 7.7967x; 1.0067x over previous
//
#include <hip/hip_runtime.h>

#define N_SPK 1024
#define M_UTT 16
#define D_DIM 512

typedef __attribute__((ext_vector_type(8))) short bf16x8;
typedef __attribute__((ext_vector_type(4))) float f32x4;

__device__ __forceinline__ float wave_sum64(float v) {
  #pragma unroll
  for (int off = 32; off >= 1; off >>= 1) v += __shfl_xor(v, off, 64);
  return v;
}

__device__ __forceinline__ unsigned short f2bf(float x) {
  unsigned int u = __float_as_uint(x);
  unsigned int r = (u + 0x7FFFu + ((u >> 16) & 1u)) >> 16;  // RNE
  return (unsigned short)r;
}

__device__ __forceinline__ unsigned int pack_bf16(float a, float b) {
  return (unsigned int)f2bf(a) | ((unsigned int)f2bf(b) << 16);
}

__device__ __forceinline__ void gload_lds16(const void* g, void* l) {
  __builtin_amdgcn_global_load_lds(
      (const __attribute__((address_space(1))) void*)g,
      (__attribute__((address_space(3))) void*)l, 16, 0, 0);
}

// Kernel 1: per speaker n — centroid unit vec (bf16), normalized embeddings
// (bf16), and the exact fp32 leave-one-out diagonal logit pos = w*(diag+eps)+b.
__global__ __launch_bounds__(256) void prep_kernel(
    const float* __restrict__ emb, const float* __restrict__ wp,
    const float* __restrict__ bp, unsigned int* __restrict__ eU,
    unsigned int* __restrict__ cU, float* __restrict__ pos_out)
{
  const int n = blockIdx.x;
  const int t = threadIdx.x;
  __shared__ float es[M_UTT * D_DIM];
  __shared__ float Sd[D_DIM];
  __shared__ float red[4];
  __shared__ float inv_s[M_UTT];

  const float* base = emb + (size_t)n * (M_UTT * D_DIM);
  #pragma unroll
  for (int i = 0; i < 8; ++i) {
    int s = t + i * 256;
    reinterpret_cast<float4*>(es)[s] = reinterpret_cast<const float4*>(base)[s];
  }
  __syncthreads();

  #pragma unroll
  for (int rep = 0; rep < 2; ++rep) {
    int d = t + rep * 256;
    float s = 0.f;
    #pragma unroll
    for (int m = 0; m < M_UTT; ++m) s += es[m * D_DIM + d];
    Sd[d] = s;
  }
  __syncthreads();

  float p = 0.f;
  #pragma unroll
  for (int rep = 0; rep < 2; ++rep) {
    int d = t + rep * 256;
    float c = Sd[d] * (1.f / M_UTT);
    p += c * c;
  }
  p = wave_sum64(p);
  if ((t & 63) == 0) red[t >> 6] = p;
  __syncthreads();
  float cn2 = red[0] + red[1] + red[2] + red[3];
  float invc = 1.f / fmaxf(sqrtf(cn2), 1e-8f);

  // centroid unit vector -> bf16 (2 elems per thread)
  {
    int d = t * 2;
    float c0 = Sd[d] * (1.f / M_UTT) * invc;
    float c1 = Sd[d + 1] * (1.f / M_UTT) * invc;
    cU[n * 256 + t] = pack_bf16(c0, c1);
  }

  // per-m diag (exact fp32) + inverse norms
  const int wid = t >> 6, lane = t & 63;
  const float w = *wp, b = *bp;
  for (int m = wid; m < M_UTT; m += 4) {
    float dot = 0.f, ne = 0.f, nl = 0.f;
    #pragma unroll
    for (int r = 0; r < 8; ++r) {
      int d = lane + r * 64;
      float e = es[m * D_DIM + d];
      float l = Sd[d] - e;
      dot += e * l; ne += e * e; nl += l * l;
    }
    dot = wave_sum64(dot); ne = wave_sum64(ne); nl = wave_sum64(nl);
    if (lane == 0) {
      float inv_e = 1.f / fmaxf(sqrtf(ne), 1e-8f);
      float inv_l = 1.f / fmaxf(sqrtf(nl) * (1.f / (M_UTT - 1)), 1e-8f);
      float diag = dot * (1.f / (M_UTT - 1)) * inv_e * inv_l;
      pos_out[n * M_UTT + m] = w * (diag + 1e-6f) + b;
      inv_s[m] = inv_e;
    }
  }
  __syncthreads();

  // normalized embeddings -> bf16 (16 iters x 2 elems)
  #pragma unroll
  for (int i = 0; i < 16; ++i) {
    int p2 = t + i * 256;            // pair index 0..4095
    int m = p2 >> 8;
    int d = (p2 & 255) * 2;
    float sc = inv_s[m];
    float x0 = es[m * D_DIM + d] * sc;
    float x1 = es[m * D_DIM + d + 1] * sc;
    eU[(size_t)n * 4096 + p2] = pack_bf16(x0, x1);
  }
}

// Kernel 2: bf16 MFMA GEMM (16384x1024x512) with fused exp epilogue.
// 128x128 block tile, BK=64, 4 waves (2x2), 64x64 per wave, 4x4 fragments.
// A/B staged via global_load_lds(16B) with pre-swizzled source; ds_read_b128
// with matching XOR swizzle (seg ^= row&7).
#define BM 128
#define BN 128
#define BK 64

__global__ __launch_bounds__(256) void mfma_kernel(
    const unsigned short* __restrict__ eU, const unsigned short* __restrict__ cU,
    const float* __restrict__ pos, const float* __restrict__ wp,
    const float* __restrict__ bp, float* __restrict__ partial)
{
  __shared__ unsigned short As[BM * BK];
  __shared__ unsigned short Bs[BN * BK];
  __shared__ float rowsum[2][BM];
  __shared__ float pos_l[BM];

  const int t = threadIdx.x;
  const int lane = t & 63;
  const int wv_id = t >> 6;            // 0..3
  const int wm = wv_id >> 1, wn = wv_id & 1;
  const int cb = blockIdx.x, rb = blockIdx.y;
  const int row0 = rb * BM, col0 = cb * BN;

  if (t < BM) pos_l[t] = pos[row0 + t];

  const float w = *wp, b = *bp;
  const float bb = w * 1e-6f + b;      // fold +SIM_EPS

  f32x4 acc[4][4] = {};

  const int lrow = lane >> 3;              // row within 8-row chunk
  const int lseg = (lane & 7) ^ lrow;      // pre-swizzled 16B-seg in source

  for (int kt = 0; kt < D_DIM / BK; ++kt) {
    const int d0 = kt * BK;
    __syncthreads();
    #pragma unroll
    for (int i = 0; i < 4; ++i) {
      int c = wv_id * 4 + i;               // chunk 0..15 (8 rows each)
      size_t gr = (size_t)(row0 + c * 8 + lrow) * D_DIM + d0 + lseg * 8;
      gload_lds16(eU + gr, (char*)As + c * 1024);
      size_t gc = (size_t)(col0 + c * 8 + lrow) * D_DIM + d0 + lseg * 8;
      gload_lds16(cU + gc, (char*)Bs + c * 1024);
    }
    __syncthreads();   // compiler drains vmcnt before barrier

    #pragma unroll
    for (int kk = 0; kk < 2; ++kk) {
      bf16x8 af[4], bf[4];
      #pragma unroll
      for (int mi = 0; mi < 4; ++mi) {
        int r = wm * 64 + mi * 16 + (lane & 15);
        int seg = ((lane >> 4) + kk * 4) ^ (r & 7);
        af[mi] = *reinterpret_cast<const bf16x8*>(
            (const char*)As + r * 128 + seg * 16);
      }
      #pragma unroll
      for (int nj = 0; nj < 4; ++nj) {
        int s = wn * 64 + nj * 16 + (lane & 15);
        int seg = ((lane >> 4) + kk * 4) ^ (s & 7);
        bf[nj] = *reinterpret_cast<const bf16x8*>(
            (const char*)Bs + s * 128 + seg * 16);
      }
      #pragma unroll
      for (int mi = 0; mi < 4; ++mi)
        #pragma unroll
        for (int nj = 0; nj < 4; ++nj)
          acc[mi][nj] = __builtin_amdgcn_mfma_f32_16x16x32_bf16(
              af[mi], bf[nj], acc[mi][nj], 0, 0, 0);
    }
  }

  // fused epilogue: arg = w*acc + bb (diag -> pos), exp, per-row sums
  float esum[4][4];
  #pragma unroll
  for (int mi = 0; mi < 4; ++mi)
    #pragma unroll
    for (int rg = 0; rg < 4; ++rg) esum[mi][rg] = 0.f;

  #pragma unroll
  for (int nj = 0; nj < 4; ++nj) {
    int kg = col0 + wn * 64 + nj * 16 + (lane & 15);
    #pragma unroll
    for (int mi = 0; mi < 4; ++mi) {
      #pragma unroll
      for (int rg = 0; rg < 4; ++rg) {
        int r_loc = wm * 64 + mi * 16 + (lane >> 4) * 4 + rg;
        float arg = w * acc[mi][nj][rg] + bb;
        if (kg == ((row0 + r_loc) >> 4)) arg = pos_l[r_loc];
        esum[mi][rg] += __expf(arg);
      }
    }
  }
  // reduce across the 16 column-lanes (same rows: lane bits 0-3)
  #pragma unroll
  for (int mi = 0; mi < 4; ++mi)
    #pragma unroll
    for (int rg = 0; rg < 4; ++rg) {
      float v = esum[mi][rg];
      v += __shfl_xor(v, 1, 64);
      v += __shfl_xor(v, 2, 64);
      v += __shfl_xor(v, 4, 64);
      v += __shfl_xor(v, 8, 64);
      esum[mi][rg] = v;
    }
  if ((lane & 15) == 0) {
    #pragma unroll
    for (int mi = 0; mi < 4; ++mi)
      #pragma unroll
      for (int rg = 0; rg < 4; ++rg)
        rowsum[wn][wm * 64 + mi * 16 + (lane >> 4) * 4 + rg] = esum[mi][rg];
  }
  __syncthreads();
  if (t < BM) partial[(size_t)cb * (N_SPK * M_UTT) + row0 + t] =
      rowsum[0][t] + rowsum[1][t];
}

__global__ __launch_bounds__(256) void finalize_kernel(
    const float* __restrict__ partial, const float* __restrict__ pos,
    float* __restrict__ bsum)
{
  const int t = threadIdx.x;
  const int r = blockIdx.x * 256 + t;
  float s = 0.f;
  #pragma unroll
  for (int cb = 0; cb < 8; ++cb) s += partial[cb * (N_SPK * M_UTT) + r];
  float v = logf(s + 1e-6f) - pos[r];
  v = wave_sum64(v);
  __shared__ float red[4];
  if ((t & 63) == 0) red[t >> 6] = v;
  __syncthreads();
  if (t == 0) bsum[blockIdx.x] = red[0] + red[1] + red[2] + red[3];
}

__global__ void final_reduce(const float* __restrict__ bsum,
                             float* __restrict__ out)
{
  float v = bsum[threadIdx.x];
  v = wave_sum64(v);
  if (threadIdx.x == 0) out[0] = v;
}

extern "C" void kernel_launch(void* const* d_in, const int* in_sizes, int n_in,
                              void* d_out, int out_size, void* d_ws, size_t ws_size,
                              hipStream_t stream) {
  const float* emb = (const float*)d_in[0];
  const float* wp  = (const float*)d_in[1];
  const float* bp  = (const float*)d_in[2];
  float* out = (float*)d_out;

  char* wsb = (char*)d_ws;
  unsigned int* eU  = (unsigned int*)wsb;                       // 16,777,216 B
  unsigned int* cU  = (unsigned int*)(wsb + 16777216);          //  1,048,576 B
  float* pos        = (float*)(wsb + 16777216 + 1048576);       //     65,536 B
  float* partial    = (float*)(wsb + 16777216 + 1048576 + 65536);   // 524,288 B
  float* bsum       = (float*)(wsb + 16777216 + 1048576 + 65536 + 524288);

  prep_kernel<<<N_SPK, 256, 0, stream>>>(emb, wp, bp, eU, cU, pos);
  dim3 grid(N_SPK / BN, (N_SPK * M_UTT) / BM);
  mfma_kernel<<<grid, 256, 0, stream>>>(
      (const unsigned short*)eU, (const unsigned short*)cU, pos, wp, bp, partial);
  finalize_kernel<<<(N_SPK * M_UTT) / 256, 256, 0, stream>>>(partial, pos, bsum);
  final_reduce<<<1, 64, 0, stream>>>(bsum, out);
}